// Round 1
// baseline (42865.863 us; speedup 1.0000x reference)
//
#include <hip/hip_runtime.h>
#include <math.h>

// Problem dims
static constexpr int B  = 256;
static constexpr int L  = 512;
static constexpr int D  = 64;
static constexpr int P  = 256;
static constexpr int H  = 512;
static constexpr int G4 = 4 * H;   // 2048 gate columns
static constexpr int NJ = 12;
static constexpr int M  = 256;
static constexpr int HOR = 9;
static constexpr float EPS = 1e-5f;

// LSTM step tile config
static constexpr int TM = 32;   // batch rows per block
static constexpr int TJ = 16;   // hidden (j) columns per block -> 64 gate cols
static constexpr int TN = 64;   // 4 gates * TJ
static constexpr int KT = 32;   // K chunk

__device__ __forceinline__ float sigmoidf_(float x) {
    return 1.0f / (1.0f + expf(-x));
}
__device__ __forceinline__ float gelu_exact(float x) {
    return 0.5f * x * (1.0f + erff(x * 0.70710678118654752f));
}

// ---------------------------------------------------------------------------
// emb = gelu(layernorm(x @ Wp + bp))   one block per (b,t) row, 256 threads
// emb layout: [(b*L + t) * P + p]
// ---------------------------------------------------------------------------
__global__ __launch_bounds__(256) void emb_kernel(
    const float* __restrict__ x, const float* __restrict__ Wp,
    const float* __restrict__ bp, const float* __restrict__ gamma,
    const float* __restrict__ beta, float* __restrict__ emb)
{
    const int row = blockIdx.x;          // b*L + t
    const int p   = threadIdx.x;         // 0..255
    __shared__ float xs[D];
    __shared__ float red[P];

    if (p < D) xs[p] = x[(size_t)row * D + p];
    __syncthreads();

    float acc = bp[p];
#pragma unroll
    for (int k = 0; k < D; ++k)
        acc = fmaf(xs[k], Wp[k * P + p], acc);

    // mean
    red[p] = acc;
    __syncthreads();
    for (int s = 128; s > 0; s >>= 1) {
        if (p < s) red[p] += red[p + s];
        __syncthreads();
    }
    const float mu = red[0] * (1.0f / (float)P);
    __syncthreads();

    const float d = acc - mu;
    red[p] = d * d;
    __syncthreads();
    for (int s = 128; s > 0; s >>= 1) {
        if (p < s) red[p] += red[p + s];
        __syncthreads();
    }
    const float var = red[0] * (1.0f / (float)P);

    float v = gamma[p] * d * rsqrtf(var + EPS) + beta[p];
    emb[(size_t)row * P + p] = gelu_exact(v);
}

// ---------------------------------------------------------------------------
// One LSTM layer timestep:
//   gates(B x 2048) = A0 @ W0^T + h_prev @ W1^T + bih + bhh
//   i,f,g,o = split(gates); c = sig(f)*c + sig(i)*tanh(g); h = sig(o)*tanh(c)
// Block computes a TM x TN tile where the TN gate columns are
// {gate*512 + j0 + jj : gate in 0..3, jj in 0..15} so the cell update is
// local to the block (fused epilogue). h double-buffered, c in-place.
// ---------------------------------------------------------------------------
__global__ __launch_bounds__(256) void lstm_step(
    const float* __restrict__ A0, int a0_stride, int K0,
    const float* __restrict__ h_prev,              // (B,H) stride H
    const float* __restrict__ W0,                  // (2048, K0) row-major
    const float* __restrict__ W1,                  // (2048, H) row-major
    const float* __restrict__ bih, const float* __restrict__ bhh,
    float* __restrict__ c,                         // (B,H) in-place
    float* __restrict__ h_out)                     // (B,H)
{
    __shared__ float As[KT][TM + 2];   // +2: keep 8B alignment for b64 reads
    __shared__ float Bs[KT][TN + 4];   // +4: keep 16B alignment for b128 reads
    __shared__ float Gs[TM][TN + 1];

    const int j0  = blockIdx.x * TJ;
    const int bm0 = blockIdx.y * TM;
    const int tid = threadIdx.x;
    const int tx  = tid & 15;          // n0 = tx*4
    const int ty  = tid >> 4;          // m0 = ty*2

    float acc[2][4] = {{0.f,0.f,0.f,0.f},{0.f,0.f,0.f,0.f}};

    const int K = K0 + H;
    const int kk = tid & 31;
    const int r0 = tid >> 5;           // 0..7

    for (int k0 = 0; k0 < K; k0 += KT) {
        const bool seg0 = (k0 < K0);
        const float* Aseg = seg0 ? A0 : h_prev;
        const int astr    = seg0 ? a0_stride : H;
        const int kb      = seg0 ? k0 : (k0 - K0);
        const float* Wseg = seg0 ? W0 : W1;
        const int wld     = seg0 ? K0 : H;

        // stage A tile (TM x KT), transposed into As[k][m]
#pragma unroll
        for (int pss = 0; pss < 4; ++pss) {
            const int m = r0 + pss * 8;
            As[kk][m] = Aseg[(size_t)(bm0 + m) * astr + kb + kk];
        }
        // stage B tile (TN x KT), transposed into Bs[k][n]
#pragma unroll
        for (int pss = 0; pss < 8; ++pss) {
            const int n = r0 + pss * 8;
            const int g = ((n >> 4) << 9) + j0 + (n & 15);   // gate*512 + j
            Bs[kk][n] = Wseg[(size_t)g * wld + kb + kk];
        }
        __syncthreads();

#pragma unroll
        for (int kz = 0; kz < KT; ++kz) {
            const float a0v = As[kz][ty * 2 + 0];
            const float a1v = As[kz][ty * 2 + 1];
            const float b0 = Bs[kz][tx * 4 + 0];
            const float b1 = Bs[kz][tx * 4 + 1];
            const float b2 = Bs[kz][tx * 4 + 2];
            const float b3 = Bs[kz][tx * 4 + 3];
            acc[0][0] = fmaf(a0v, b0, acc[0][0]);
            acc[0][1] = fmaf(a0v, b1, acc[0][1]);
            acc[0][2] = fmaf(a0v, b2, acc[0][2]);
            acc[0][3] = fmaf(a0v, b3, acc[0][3]);
            acc[1][0] = fmaf(a1v, b0, acc[1][0]);
            acc[1][1] = fmaf(a1v, b1, acc[1][1]);
            acc[1][2] = fmaf(a1v, b2, acc[1][2]);
            acc[1][3] = fmaf(a1v, b3, acc[1][3]);
        }
        __syncthreads();
    }

    // epilogue: add bias, park gates in LDS
#pragma unroll
    for (int q = 0; q < 2; ++q) {
#pragma unroll
        for (int i = 0; i < 4; ++i) {
            const int n = tx * 4 + i;
            const int m = ty * 2 + q;
            const int g = ((n >> 4) << 9) + j0 + (n & 15);
            Gs[m][n] = acc[q][i] + bih[g] + bhh[g];
        }
    }
    __syncthreads();

    // cell update: TM*TJ = 512 (m,jj) pairs, 2 per thread
#pragma unroll
    for (int pp = 0; pp < 2; ++pp) {
        const int pr = tid + pp * 256;
        const int m  = pr >> 4;
        const int jj = pr & 15;
        const float iv = sigmoidf_(Gs[m][jj]);
        const float fv = sigmoidf_(Gs[m][16 + jj]);
        const float gv = tanhf(Gs[m][32 + jj]);
        const float ov = sigmoidf_(Gs[m][48 + jj]);
        const size_t idx = (size_t)(bm0 + m) * H + j0 + jj;
        const float cv = fv * c[idx] + iv * gv;
        c[idx] = cv;
        h_out[idx] = ov * tanhf(cv);
    }
}

// ---------------------------------------------------------------------------
// head: per batch row b, j = joint_index[b]:
//   z = gelu(h_last[b] @ Wh1[j] + bh1[j]);  out[b] = z @ Wh2[j] + bh2[j]
// one block per b, 256 threads
// ---------------------------------------------------------------------------
__global__ __launch_bounds__(256) void head_kernel(
    const float* __restrict__ h_last, const int* __restrict__ joint_index,
    const float* __restrict__ Wh1, const float* __restrict__ bh1,
    const float* __restrict__ Wh2, const float* __restrict__ bh2,
    float* __restrict__ out)
{
    const int b = blockIdx.x;
    const int t = threadIdx.x;
    const int j = joint_index[b];
    __shared__ float hs[H];
    __shared__ float zs[M];

    hs[t]       = h_last[(size_t)b * H + t];
    hs[t + 256] = h_last[(size_t)b * H + 256 + t];
    __syncthreads();

    float acc = bh1[j * M + t];
    const float* w = Wh1 + (size_t)j * H * M + t;   // Wh1[j][k][t]
#pragma unroll 8
    for (int k = 0; k < H; ++k)
        acc = fmaf(hs[k], w[(size_t)k * M], acc);

    zs[t] = gelu_exact(acc);
    __syncthreads();

    if (t < HOR) {
        float a = bh2[j * HOR + t];
        const float* w2 = Wh2 + (size_t)j * M * HOR + t;
        for (int m = 0; m < M; ++m)
            a = fmaf(zs[m], w2[(size_t)m * HOR], a);
        out[(size_t)b * HOR + t] = a;
    }
}

// ---------------------------------------------------------------------------
extern "C" void kernel_launch(void* const* d_in, const int* in_sizes, int n_in,
                              void* d_out, int out_size, void* d_ws, size_t ws_size,
                              hipStream_t stream)
{
    const float* x     = (const float*)d_in[0];
    const int*   joint = (const int*)  d_in[1];
    const float* Wp    = (const float*)d_in[2];
    const float* bp    = (const float*)d_in[3];
    const float* gamma = (const float*)d_in[4];
    const float* beta  = (const float*)d_in[5];
    const float* Wih0  = (const float*)d_in[6];
    const float* Whh0  = (const float*)d_in[7];
    const float* bih0  = (const float*)d_in[8];
    const float* bhh0  = (const float*)d_in[9];
    const float* Wih1  = (const float*)d_in[10];
    const float* Whh1  = (const float*)d_in[11];
    const float* bih1  = (const float*)d_in[12];
    const float* bhh1  = (const float*)d_in[13];
    const float* Wh1   = (const float*)d_in[14];
    const float* bh1   = (const float*)d_in[15];
    const float* Wh2   = (const float*)d_in[16];
    const float* bh2   = (const float*)d_in[17];
    float* out = (float*)d_out;

    // workspace layout (floats)
    float* emb    = (float*)d_ws;                        // B*L*P = 33,554,432
    float* states = emb + (size_t)B * L * P;
    float* h0a = states;                                 // each B*H = 131072
    float* h0b = h0a + (size_t)B * H;
    float* c0  = h0b + (size_t)B * H;
    float* h1a = c0  + (size_t)B * H;
    float* h1b = h1a + (size_t)B * H;
    float* c1  = h1b + (size_t)B * H;

    // zero h0a, c0, h1a, c1 (and the alt buffers, harmless) — ws is poisoned
    hipMemsetAsync(states, 0, sizeof(float) * 6 * (size_t)B * H, stream);

    emb_kernel<<<B * L, 256, 0, stream>>>(x, Wp, bp, gamma, beta, emb);

    dim3 sgrid(H / TJ, B / TM);   // (32, 8) = 256 blocks
    for (int t = 0; t < L; ++t) {
        const float* h0p = (t & 1) ? h0b : h0a;
        float*       h0c = (t & 1) ? h0a : h0b;
        const float* h1p = (t & 1) ? h1b : h1a;
        float*       h1c = (t & 1) ? h1a : h1b;
        // layer 0: A0 = emb[:, t, :]  (row stride L*P), K0 = P
        lstm_step<<<sgrid, 256, 0, stream>>>(emb + (size_t)t * P, L * P, P,
                                             h0p, Wih0, Whh0, bih0, bhh0,
                                             c0, h0c);
        // layer 1: A0 = h0_t (row stride H), K0 = H
        lstm_step<<<sgrid, 256, 0, stream>>>(h0c, H, H,
                                             h1p, Wih1, Whh1, bih1, bhh1,
                                             c1, h1c);
    }
    // after t=511 (odd), final h1 is in h1a
    head_kernel<<<B, 256, 0, stream>>>(h1a, joint, Wh1, bh1, Wh2, bh2, out);
}

// Round 2
// 34422.061 us; speedup vs baseline: 1.2453x; 1.2453x over previous
//
#include <hip/hip_runtime.h>
#include <math.h>

// Problem dims
static constexpr int B  = 256;
static constexpr int L  = 512;
static constexpr int D  = 64;
static constexpr int P  = 256;
static constexpr int H  = 512;
static constexpr int M  = 256;
static constexpr int HOR = 9;
static constexpr float EPS = 1e-5f;

// Step-GEMM tile config: 128 threads, 32(m) x 64(n) tile, 4x4 per thread
static constexpr int TM = 32;
static constexpr int TJ = 16;   // j's per block (n = 4 gates x TJ)
static constexpr int TN = 64;
static constexpr int KT = 32;

__device__ __forceinline__ float sigmoidf_(float x) {
    return 1.0f / (1.0f + expf(-x));
}
__device__ __forceinline__ float gelu_exact(float x) {
    return 0.5f * x * (1.0f + erff(x * 0.70710678118654752f));
}

// ---------------------------------------------------------------------------
// emb = gelu(layernorm(x @ Wp + bp)), stored T-MAJOR: emb[(t*B + b)*P + p]
// so each timestep's A-slab is a contiguous 256KB block.
// ---------------------------------------------------------------------------
__global__ __launch_bounds__(256) void emb_kernel(
    const float* __restrict__ x, const float* __restrict__ Wp,
    const float* __restrict__ bp, const float* __restrict__ gamma,
    const float* __restrict__ beta, float* __restrict__ embt)
{
    const int row = blockIdx.x;          // b*L + t
    const int b   = row >> 9;            // /L
    const int t   = row & (L - 1);
    const int p   = threadIdx.x;         // 0..255
    __shared__ float xs[D];
    __shared__ float red[P];

    if (p < D) xs[p] = x[(size_t)row * D + p];
    __syncthreads();

    float acc = bp[p];
#pragma unroll
    for (int k = 0; k < D; ++k)
        acc = fmaf(xs[k], Wp[k * P + p], acc);

    red[p] = acc;
    __syncthreads();
    for (int s = 128; s > 0; s >>= 1) {
        if (p < s) red[p] += red[p + s];
        __syncthreads();
    }
    const float mu = red[0] * (1.0f / (float)P);
    __syncthreads();

    const float d = acc - mu;
    red[p] = d * d;
    __syncthreads();
    for (int s = 128; s > 0; s >>= 1) {
        if (p < s) red[p] += red[p + s];
        __syncthreads();
    }
    const float var = red[0] * (1.0f / (float)P);

    float v = gamma[p] * d * rsqrtf(var + EPS) + beta[p];
    embt[((size_t)t * B + b) * P + p] = gelu_exact(v);
}

// ---------------------------------------------------------------------------
// Launch A (per timestep), grid (32, 8, 2), 128 threads:
//   role 0 (z=0): gates0 = [emb_t | h0_prev] @ [Wih0|Whh0]^T + bias
//                 -> fused LSTM pointwise -> c0, h0_out
//                 (n columns gate-interleaved: n -> g = (n>>4)*512 + j0 + (n&15))
//   role 1 (z=1): partial1 = h1_prev @ Whh1^T   (plain n columns)
// Both roles co-resident: 2 blocks/CU.
// ---------------------------------------------------------------------------
__global__ __launch_bounds__(128) void lstm_stepA(
    const float* __restrict__ embt, int t,
    const float* __restrict__ h0_prev, const float* __restrict__ h1_prev,
    const float* __restrict__ Wih0, const float* __restrict__ Whh0,
    const float* __restrict__ bih0, const float* __restrict__ bhh0,
    const float* __restrict__ Whh1,
    float* __restrict__ c0, float* __restrict__ h0_out,
    float* __restrict__ partial1)
{
    __shared__ float As[KT][TM + 4];   // stride 36 floats = 144B (16B-aligned rows)
    __shared__ float Bs[KT][TN + 4];   // stride 68 floats = 272B; reused as gate park

    const int role = blockIdx.z;
    const int nblk = blockIdx.x;       // 0..31
    const int bm0  = blockIdx.y * TM;
    const int j0   = nblk * TJ;
    const int tid  = threadIdx.x;
    const int tx   = tid & 15;         // n0 = tx*4
    const int ty   = tid >> 4;         // m0 = ty*4

    // staging coords
    const int kq = (tid & 7) * 4;      // k sub-offset (float4)
    const int rw = tid >> 3;           // 0..15 staging row

    // B-tile global row indices for the 4 staging passes
    int grow[4];
#pragma unroll
    for (int ps = 0; ps < 4; ++ps) {
        const int n = rw + ps * 16;
        grow[ps] = role ? (nblk * TN + n)
                        : (((n >> 4) << 9) + j0 + (n & 15));
    }

    float acc[4][4] = {{0.f,0.f,0.f,0.f},{0.f,0.f,0.f,0.f},
                       {0.f,0.f,0.f,0.f},{0.f,0.f,0.f,0.f}};

    const float* emb_slab = embt + (size_t)t * B * P;
    const int K = role ? H : (P + H);

    for (int k0 = 0; k0 < K; k0 += KT) {
        const float* Aseg; int astr, kb;
        const float* Bseg; int wld;
        if (role)        { Aseg = h1_prev;  astr = H; kb = k0;     Bseg = Whh1; wld = H; }
        else if (k0 < P) { Aseg = emb_slab; astr = P; kb = k0;     Bseg = Wih0; wld = P; }
        else             { Aseg = h0_prev;  astr = H; kb = k0 - P; Bseg = Whh0; wld = H; }

        // stage A (TM x KT) transposed
#pragma unroll
        for (int ps = 0; ps < 2; ++ps) {
            const int m = rw + ps * 16;
            const float4 v = *(const float4*)&Aseg[(size_t)(bm0 + m) * astr + kb + kq];
            As[kq + 0][m] = v.x; As[kq + 1][m] = v.y;
            As[kq + 2][m] = v.z; As[kq + 3][m] = v.w;
        }
        // stage B (TN x KT) transposed
#pragma unroll
        for (int ps = 0; ps < 4; ++ps) {
            const int n = rw + ps * 16;
            const float4 v = *(const float4*)&Bseg[(size_t)grow[ps] * wld + kb + kq];
            Bs[kq + 0][n] = v.x; Bs[kq + 1][n] = v.y;
            Bs[kq + 2][n] = v.z; Bs[kq + 3][n] = v.w;
        }
        __syncthreads();

#pragma unroll
        for (int kz = 0; kz < KT; ++kz) {
            const float4 av = *(const float4*)&As[kz][ty * 4];  // 16-lane broadcast
            const float4 bv = *(const float4*)&Bs[kz][tx * 4];  // 2-way (free)
            const float a[4] = {av.x, av.y, av.z, av.w};
            const float b[4] = {bv.x, bv.y, bv.z, bv.w};
#pragma unroll
            for (int im = 0; im < 4; ++im)
#pragma unroll
                for (int in = 0; in < 4; ++in)
                    acc[im][in] = fmaf(a[im], b[in], acc[im][in]);
        }
        __syncthreads();
    }

    if (role) {
        // plain store of h1 partial
#pragma unroll
        for (int im = 0; im < 4; ++im) {
            float4 v = {acc[im][0], acc[im][1], acc[im][2], acc[im][3]};
            *(float4*)&partial1[(size_t)(bm0 + ty * 4 + im) * 2048 + nblk * TN + tx * 4] = v;
        }
    } else {
        // add bias, park gates in Bs (free after last barrier)
#pragma unroll
        for (int in = 0; in < 4; ++in) {
            const int n = tx * 4 + in;
            const int g = ((n >> 4) << 9) + j0 + (n & 15);
            const float bias = bih0[g] + bhh0[g];
#pragma unroll
            for (int im = 0; im < 4; ++im)
                Bs[ty * 4 + im][n] = acc[im][in] + bias;
        }
        __syncthreads();
        // fused LSTM cell update: 32x16 (m,jj) pairs, 4 per thread
#pragma unroll
        for (int p = 0; p < 4; ++p) {
            const int pr = tid + p * 128;
            const int m  = pr >> 4;
            const int jj = pr & 15;
            const float iv = sigmoidf_(Bs[m][jj]);
            const float fv = sigmoidf_(Bs[m][16 + jj]);
            const float gv = tanhf(Bs[m][32 + jj]);
            const float ov = sigmoidf_(Bs[m][48 + jj]);
            const size_t idx = (size_t)(bm0 + m) * H + j0 + jj;
            const float cv = fv * c0[idx] + iv * gv;
            c0[idx] = cv;
            h0_out[idx] = ov * tanhf(cv);
        }
    }
}

// ---------------------------------------------------------------------------
// Launch B (per timestep), grid (32, 8), 128 threads:
//   gates1 = partial1 + h0_cur @ Wih1^T + bih1 + bhh1 -> pointwise -> c1, h1_out
// ---------------------------------------------------------------------------
__global__ __launch_bounds__(128) void lstm_stepB(
    const float* __restrict__ h0_cur, const float* __restrict__ partial1,
    const float* __restrict__ Wih1,
    const float* __restrict__ bih1, const float* __restrict__ bhh1,
    float* __restrict__ c1, float* __restrict__ h1_out)
{
    __shared__ float As[KT][TM + 4];
    __shared__ float Bs[KT][TN + 4];

    const int nblk = blockIdx.x;
    const int bm0  = blockIdx.y * TM;
    const int j0   = nblk * TJ;
    const int tid  = threadIdx.x;
    const int tx   = tid & 15;
    const int ty   = tid >> 4;

    const int kq = (tid & 7) * 4;
    const int rw = tid >> 3;

    int grow[4];
#pragma unroll
    for (int ps = 0; ps < 4; ++ps) {
        const int n = rw + ps * 16;
        grow[ps] = ((n >> 4) << 9) + j0 + (n & 15);
    }

    float acc[4][4] = {{0.f,0.f,0.f,0.f},{0.f,0.f,0.f,0.f},
                       {0.f,0.f,0.f,0.f},{0.f,0.f,0.f,0.f}};

    for (int k0 = 0; k0 < H; k0 += KT) {
#pragma unroll
        for (int ps = 0; ps < 2; ++ps) {
            const int m = rw + ps * 16;
            const float4 v = *(const float4*)&h0_cur[(size_t)(bm0 + m) * H + k0 + kq];
            As[kq + 0][m] = v.x; As[kq + 1][m] = v.y;
            As[kq + 2][m] = v.z; As[kq + 3][m] = v.w;
        }
#pragma unroll
        for (int ps = 0; ps < 4; ++ps) {
            const int n = rw + ps * 16;
            const float4 v = *(const float4*)&Wih1[(size_t)grow[ps] * H + k0 + kq];
            Bs[kq + 0][n] = v.x; Bs[kq + 1][n] = v.y;
            Bs[kq + 2][n] = v.z; Bs[kq + 3][n] = v.w;
        }
        __syncthreads();

#pragma unroll
        for (int kz = 0; kz < KT; ++kz) {
            const float4 av = *(const float4*)&As[kz][ty * 4];
            const float4 bv = *(const float4*)&Bs[kz][tx * 4];
            const float a[4] = {av.x, av.y, av.z, av.w};
            const float b[4] = {bv.x, bv.y, bv.z, bv.w};
#pragma unroll
            for (int im = 0; im < 4; ++im)
#pragma unroll
                for (int in = 0; in < 4; ++in)
                    acc[im][in] = fmaf(a[im], b[in], acc[im][in]);
        }
        __syncthreads();
    }

    // epilogue: + partial1 + bias, park in Bs, pointwise
    {
        const int gbase = (((tx * 4) >> 4) << 9) + j0 + ((tx * 4) & 15);
#pragma unroll
        for (int im = 0; im < 4; ++im) {
            const float4 p4 = *(const float4*)&partial1[(size_t)(bm0 + ty * 4 + im) * 2048 + gbase];
            const float pp[4] = {p4.x, p4.y, p4.z, p4.w};
#pragma unroll
            for (int in = 0; in < 4; ++in) {
                const int n = tx * 4 + in;
                const int g = gbase + in;
                Bs[ty * 4 + im][n] = acc[im][in] + pp[in] + bih1[g] + bhh1[g];
            }
        }
    }
    __syncthreads();
#pragma unroll
    for (int p = 0; p < 4; ++p) {
        const int pr = tid + p * 128;
        const int m  = pr >> 4;
        const int jj = pr & 15;
        const float iv = sigmoidf_(Bs[m][jj]);
        const float fv = sigmoidf_(Bs[m][16 + jj]);
        const float gv = tanhf(Bs[m][32 + jj]);
        const float ov = sigmoidf_(Bs[m][48 + jj]);
        const size_t idx = (size_t)(bm0 + m) * H + j0 + jj;
        const float cv = fv * c1[idx] + iv * gv;
        c1[idx] = cv;
        h1_out[idx] = ov * tanhf(cv);
    }
}

// ---------------------------------------------------------------------------
// head: per batch row b, j = joint_index[b]
// ---------------------------------------------------------------------------
__global__ __launch_bounds__(256) void head_kernel(
    const float* __restrict__ h_last, const int* __restrict__ joint_index,
    const float* __restrict__ Wh1, const float* __restrict__ bh1,
    const float* __restrict__ Wh2, const float* __restrict__ bh2,
    float* __restrict__ out)
{
    const int b = blockIdx.x;
    const int t = threadIdx.x;
    const int j = joint_index[b];
    __shared__ float hs[H];
    __shared__ float zs[M];

    hs[t]       = h_last[(size_t)b * H + t];
    hs[t + 256] = h_last[(size_t)b * H + 256 + t];
    __syncthreads();

    float acc = bh1[j * M + t];
    const float* w = Wh1 + (size_t)j * H * M + t;
#pragma unroll 8
    for (int k = 0; k < H; ++k)
        acc = fmaf(hs[k], w[(size_t)k * M], acc);

    zs[t] = gelu_exact(acc);
    __syncthreads();

    if (t < HOR) {
        float a = bh2[j * HOR + t];
        const float* w2 = Wh2 + (size_t)j * M * HOR + t;
        for (int m = 0; m < M; ++m)
            a = fmaf(zs[m], w2[(size_t)m * HOR], a);
        out[(size_t)b * HOR + t] = a;
    }
}

// ---------------------------------------------------------------------------
extern "C" void kernel_launch(void* const* d_in, const int* in_sizes, int n_in,
                              void* d_out, int out_size, void* d_ws, size_t ws_size,
                              hipStream_t stream)
{
    const float* x     = (const float*)d_in[0];
    const int*   joint = (const int*)  d_in[1];
    const float* Wp    = (const float*)d_in[2];
    const float* bp    = (const float*)d_in[3];
    const float* gamma = (const float*)d_in[4];
    const float* beta  = (const float*)d_in[5];
    const float* Wih0  = (const float*)d_in[6];
    const float* Whh0  = (const float*)d_in[7];
    const float* bih0  = (const float*)d_in[8];
    const float* bhh0  = (const float*)d_in[9];
    const float* Wih1  = (const float*)d_in[10];
    const float* Whh1  = (const float*)d_in[11];
    const float* bih1  = (const float*)d_in[12];
    const float* bhh1  = (const float*)d_in[13];
    const float* Wh1   = (const float*)d_in[14];
    const float* bh1   = (const float*)d_in[15];
    const float* Wh2   = (const float*)d_in[16];
    const float* bh2   = (const float*)d_in[17];
    float* out = (float*)d_out;

    // workspace layout (floats)
    float* embt   = (float*)d_ws;                        // L*B*P
    float* states = embt + (size_t)L * B * P;
    float* h0a = states;
    float* h0b = h0a + (size_t)B * H;
    float* c0  = h0b + (size_t)B * H;
    float* h1a = c0  + (size_t)B * H;
    float* h1b = h1a + (size_t)B * H;
    float* c1  = h1b + (size_t)B * H;
    float* partial1 = c1 + (size_t)B * H;                // B * 2048

    hipMemsetAsync(states, 0, sizeof(float) * 6 * (size_t)B * H, stream);

    emb_kernel<<<B * L, 256, 0, stream>>>(x, Wp, bp, gamma, beta, embt);

    const dim3 gridA(H / TJ, B / TM, 2);   // (32, 8, 2) = 512 blocks
    const dim3 gridB(H / TJ, B / TM);      // (32, 8)    = 256 blocks
    for (int t = 0; t < L; ++t) {
        const float* h0p = (t & 1) ? h0b : h0a;
        float*       h0c = (t & 1) ? h0a : h0b;
        const float* h1p = (t & 1) ? h1b : h1a;
        float*       h1c = (t & 1) ? h1a : h1b;
        lstm_stepA<<<gridA, 128, 0, stream>>>(embt, t, h0p, h1p,
                                              Wih0, Whh0, bih0, bhh0, Whh1,
                                              c0, h0c, partial1);
        lstm_stepB<<<gridB, 128, 0, stream>>>(h0c, partial1, Wih1, bih1, bhh1,
                                              c1, h1c);
    }
    // t=511 odd -> final h1 in h1a
    head_kernel<<<B, 256, 0, stream>>>(h1a, joint, Wh1, bh1, Wh2, bh2, out);
}

// Round 3
// 19010.991 us; speedup vs baseline: 2.2548x; 1.8106x over previous
//
#include <hip/hip_runtime.h>
#include <math.h>

typedef __bf16 bf16;
typedef __attribute__((ext_vector_type(8))) __bf16 bf16x8;
typedef __attribute__((ext_vector_type(4))) float f32x4;

static constexpr int B = 256, L = 512, D = 64, P = 256, H = 512, M = 256, HOR = 9;
static constexpr int G = 2048;        // 4*H gate columns
static constexpr int K0 = P + H;      // 768  (layer0 K: emb | h0_prev)
static constexpr int K1 = 2 * H;      // 1024 (layer1 K: h0 | h1_prev)
static constexpr float EPS = 1e-5f;

#define MFMA(a, b, c) __builtin_amdgcn_mfma_f32_16x16x32_bf16((a), (b), (c), 0, 0, 0)

__device__ __forceinline__ float sigmoidf_(float x) { return 1.0f / (1.0f + expf(-x)); }
__device__ __forceinline__ float gelu_exact(float x) {
    return 0.5f * x * (1.0f + erff(x * 0.70710678118654752f));
}

// Accumulate one K-segment. A frags: lane reads 8 contiguous k at row (lane&15),
// m-frag1 at +16 rows. B frags: W rows g=(gate)*512+j0+(lane&15); n-frag1 at
// +512 rows (next gate). 3-pass hi/lo split (lo x lo dropped).
template <bool AL>
__device__ __forceinline__ void seg_accum(
    const bf16* __restrict__ ah, const bf16* __restrict__ al, long ldA,
    const bf16* __restrict__ bh, const bf16* __restrict__ bl, long ldB,
    int ksteps, f32x4 (&acc)[2][2])
{
    const long a1 = 16 * ldA;
    const long b1 = 512 * ldB;
#pragma unroll 4
    for (int s = 0; s < ksteps; ++s) {
        bf16x8 A0  = *(const bf16x8*)(ah);
        bf16x8 A1  = *(const bf16x8*)(ah + a1);
        bf16x8 B0h = *(const bf16x8*)(bh);
        bf16x8 B1h = *(const bf16x8*)(bh + b1);
        bf16x8 B0l = *(const bf16x8*)(bl);
        bf16x8 B1l = *(const bf16x8*)(bl + b1);
        acc[0][0] = MFMA(A0, B0h, acc[0][0]);
        acc[0][1] = MFMA(A0, B1h, acc[0][1]);
        acc[1][0] = MFMA(A1, B0h, acc[1][0]);
        acc[1][1] = MFMA(A1, B1h, acc[1][1]);
        acc[0][0] = MFMA(A0, B0l, acc[0][0]);
        acc[0][1] = MFMA(A0, B1l, acc[0][1]);
        acc[1][0] = MFMA(A1, B0l, acc[1][0]);
        acc[1][1] = MFMA(A1, B1l, acc[1][1]);
        if (AL) {
            bf16x8 A0l = *(const bf16x8*)(al);
            bf16x8 A1l = *(const bf16x8*)(al + a1);
            acc[0][0] = MFMA(A0l, B0h, acc[0][0]);
            acc[0][1] = MFMA(A0l, B1h, acc[0][1]);
            acc[1][0] = MFMA(A1l, B0h, acc[1][0]);
            acc[1][1] = MFMA(A1l, B1h, acc[1][1]);
        }
        ah += 32; al += 32; bh += 32; bl += 32;
    }
}

// ---------------------------------------------------------------------------
// emb = gelu(LN(x@Wp+bp)) -> bf16 hi/lo, T-MAJOR: [(t*B + b)*P + p]
// ---------------------------------------------------------------------------
__global__ __launch_bounds__(256) void emb_kernel(
    const float* __restrict__ x, const float* __restrict__ Wp,
    const float* __restrict__ bp, const float* __restrict__ gamma,
    const float* __restrict__ beta, bf16* __restrict__ ehi,
    bf16* __restrict__ elo, int use_elo)
{
    const int row = blockIdx.x;          // b*L + t
    const int b   = row >> 9;
    const int t   = row & (L - 1);
    const int p   = threadIdx.x;
    __shared__ float xs[D];
    __shared__ float red[P];

    if (p < D) xs[p] = x[(size_t)row * D + p];
    __syncthreads();

    float acc = bp[p];
#pragma unroll
    for (int k = 0; k < D; ++k) acc = fmaf(xs[k], Wp[k * P + p], acc);

    red[p] = acc;
    __syncthreads();
    for (int s = 128; s > 0; s >>= 1) { if (p < s) red[p] += red[p + s]; __syncthreads(); }
    const float mu = red[0] * (1.0f / (float)P);
    __syncthreads();
    const float d = acc - mu;
    red[p] = d * d;
    __syncthreads();
    for (int s = 128; s > 0; s >>= 1) { if (p < s) red[p] += red[p + s]; __syncthreads(); }
    const float var = red[0] * (1.0f / (float)P);

    const float v = gelu_exact(gamma[p] * d * rsqrtf(var + EPS) + beta[p]);
    const size_t o = ((size_t)t * B + b) * P + p;
    const bf16 hh = (bf16)v;
    ehi[o] = hh;
    if (use_elo) elo[o] = (bf16)(v - (float)hh);
}

// ---------------------------------------------------------------------------
// weight prep: W0cat = [Wih0 | Whh0] (2048 x 768), W1cat = [Wih1 | Whh1]
// (2048 x 1024), split hi/lo bf16.
// ---------------------------------------------------------------------------
__global__ __launch_bounds__(256) void prep_w0(
    const float* __restrict__ Wih0, const float* __restrict__ Whh0,
    bf16* __restrict__ hi, bf16* __restrict__ lo)
{
    const int k = blockIdx.x * 256 + threadIdx.x;   // grid.x = 3
    const int g = blockIdx.y;
    const float v = (k < P) ? Wih0[(size_t)g * P + k] : Whh0[(size_t)g * H + (k - P)];
    const bf16 h = (bf16)v;
    const size_t o = (size_t)g * K0 + k;
    hi[o] = h; lo[o] = (bf16)(v - (float)h);
}

__global__ __launch_bounds__(256) void prep_w1(
    const float* __restrict__ Wih1, const float* __restrict__ Whh1,
    bf16* __restrict__ hi, bf16* __restrict__ lo)
{
    const int k = blockIdx.x * 256 + threadIdx.x;   // grid.x = 4
    const int g = blockIdx.y;
    const float v = (k < H) ? Wih1[(size_t)g * H + k] : Whh1[(size_t)g * H + (k - H)];
    const bf16 h = (bf16)v;
    const size_t o = (size_t)g * K1 + k;
    hi[o] = h; lo[o] = (bf16)(v - (float)h);
}

__global__ __launch_bounds__(256) void prep_bias(
    const float* __restrict__ bih0, const float* __restrict__ bhh0,
    const float* __restrict__ bih1, const float* __restrict__ bhh1,
    float* __restrict__ bsum0, float* __restrict__ bsum1)
{
    const int g = blockIdx.x * 256 + threadIdx.x;   // grid.x = 8
    bsum0[g] = bih0[g] + bhh0[g];
    bsum1[g] = bih1[g] + bhh1[g];
}

// ---------------------------------------------------------------------------
// tick t: blocks 0..127 = layer0 step t (if t<512),
//         blocks 128..255 = layer1 step t-1 (if t>=1).
// Block: 64 batch x 64 gate-cols (16 j x 4 gates, n = gate*16+jj ->
// g = gate*512 + j0 + jj). 4 waves as 2x2, each wave 2x2 16x16 MFMA frags.
// h buffers: h0 write buf[t&1], read buf[(t-1)&1]; L1 reads h0 buf[(t-1)&1],
// h1 read buf[t&1], write buf[(t-1)&1]. c in-place (unique owner per elem).
// ---------------------------------------------------------------------------
__global__ __launch_bounds__(256) void tick_kernel(
    int t, int use_elo,
    const bf16* __restrict__ ehi, const bf16* __restrict__ elo,
    const bf16* __restrict__ W0hi, const bf16* __restrict__ W0lo,
    const bf16* __restrict__ W1hi, const bf16* __restrict__ W1lo,
    const float* __restrict__ bsum0, const float* __restrict__ bsum1,
    bf16* __restrict__ h0hi0, bf16* __restrict__ h0lo0,
    bf16* __restrict__ h0hi1, bf16* __restrict__ h0lo1,
    bf16* __restrict__ h1hi0, bf16* __restrict__ h1lo0,
    bf16* __restrict__ h1hi1, bf16* __restrict__ h1lo1,
    float* __restrict__ c0, float* __restrict__ c1)
{
    const int layer = blockIdx.x >> 7;
    if (layer == 0 && t >= L) return;
    if (layer == 1 && t < 1) return;
    const int idx = blockIdx.x & 127;
    const int mg = idx >> 5, ng = idx & 31;
    const int bm0 = mg * 64, j0 = ng * 16;

    const int tid  = threadIdx.x;
    const int lane = tid & 63, wid = tid >> 6;
    const int wm = wid >> 1, wn = wid & 1;
    const int rA   = lane & 15;
    const int koff = (lane >> 4) * 8;

    const int p0 = t & 1;
    // h0: read buf[(t-1)&1] = buf[1-p0]
    const bf16* h0r_hi = p0 ? h0hi0 : h0hi1;
    const bf16* h0r_lo = p0 ? h0lo0 : h0lo1;
    bf16* h0w_hi = p0 ? h0hi1 : h0hi0;
    bf16* h0w_lo = p0 ? h0lo1 : h0lo0;
    // h1: read buf[t&1] = buf[p0], write buf[1-p0]
    const bf16* h1r_hi = p0 ? h1hi1 : h1hi0;
    const bf16* h1r_lo = p0 ? h1lo1 : h1lo0;
    bf16* h1w_hi = p0 ? h1hi0 : h1hi1;
    bf16* h1w_lo = p0 ? h1lo0 : h1lo1;

    __shared__ float Gs[64][68];

    f32x4 acc[2][2] = {};

    const long arow = bm0 + wm * 32 + rA;

    if (layer == 0) {
        // segment 1: emb_t (K = 256)
        const size_t eo = ((size_t)t * B + arow) * P + koff;
        const bf16* bh = W0hi + (size_t)((wn * 2) * 512 + j0 + rA) * K0 + koff;
        const bf16* bl = W0lo + (size_t)((wn * 2) * 512 + j0 + rA) * K0 + koff;
        if (use_elo)
            seg_accum<true >(ehi + eo, elo + eo, P, bh, bl, K0, P / 32, acc);
        else
            seg_accum<false>(ehi + eo, elo + eo, P, bh, bl, K0, P / 32, acc);
        // segment 2: h0_prev (K = 512), W0 columns 256..767
        const size_t ho = (size_t)arow * H + koff;
        seg_accum<true>(h0r_hi + ho, h0r_lo + ho, H, bh + P, bl + P, K0, H / 32, acc);
    } else {
        // segment 1: h0[t-1] (K = 512)
        const size_t ho = (size_t)arow * H + koff;
        const bf16* bh = W1hi + (size_t)((wn * 2) * 512 + j0 + rA) * K1 + koff;
        const bf16* bl = W1lo + (size_t)((wn * 2) * 512 + j0 + rA) * K1 + koff;
        seg_accum<true>(h0r_hi + ho, h0r_lo + ho, H, bh, bl, K1, H / 32, acc);
        // segment 2: h1[t-2] (K = 512), W1 columns 512..1023
        seg_accum<true>(h1r_hi + ho, h1r_lo + ho, H, bh + H, bl + H, K1, H / 32, acc);
    }

    // park gates in LDS (C/D layout: col = lane&15, row = (lane>>4)*4 + reg)
#pragma unroll
    for (int mi = 0; mi < 2; ++mi)
#pragma unroll
        for (int ni = 0; ni < 2; ++ni) {
            const int ml = wm * 32 + mi * 16 + (lane >> 4) * 4;
            const int nl = wn * 32 + ni * 16 + (lane & 15);
#pragma unroll
            for (int r = 0; r < 4; ++r) Gs[ml + r][nl] = acc[mi][ni][r];
        }
    __syncthreads();

    const float* bs = layer ? bsum1 : bsum0;
    float* cc = layer ? c1 : c0;
    bf16* hwh = layer ? h1w_hi : h0w_hi;
    bf16* hwl = layer ? h1w_lo : h0w_lo;

#pragma unroll
    for (int p = 0; p < 4; ++p) {
        const int pr = tid + p * 256;
        const int m = pr >> 4, jj = pr & 15;
        const int j = j0 + jj;
        const float iraw = Gs[m][jj]      + bs[j];
        const float fraw = Gs[m][16 + jj] + bs[512 + j];
        const float graw = Gs[m][32 + jj] + bs[1024 + j];
        const float oraw = Gs[m][48 + jj] + bs[1536 + j];
        const size_t ix = (size_t)(bm0 + m) * H + j;
        const float cv = sigmoidf_(fraw) * cc[ix] + sigmoidf_(iraw) * tanhf(graw);
        cc[ix] = cv;
        const float hv = sigmoidf_(oraw) * tanhf(cv);
        const bf16 hh = (bf16)hv;
        hwh[ix] = hh;
        hwl[ix] = (bf16)(hv - (float)hh);
    }
}

// ---------------------------------------------------------------------------
// head: per batch row b, j = joint_index[b]; h reconstructed from hi+lo
// ---------------------------------------------------------------------------
__global__ __launch_bounds__(256) void head_kernel(
    const bf16* __restrict__ h_hi, const bf16* __restrict__ h_lo,
    const int* __restrict__ joint_index,
    const float* __restrict__ Wh1, const float* __restrict__ bh1,
    const float* __restrict__ Wh2, const float* __restrict__ bh2,
    float* __restrict__ out)
{
    const int b = blockIdx.x;
    const int t = threadIdx.x;
    const int j = joint_index[b];
    __shared__ float hs[H];
    __shared__ float zs[M];

    hs[t]       = (float)h_hi[(size_t)b * H + t]       + (float)h_lo[(size_t)b * H + t];
    hs[t + 256] = (float)h_hi[(size_t)b * H + 256 + t] + (float)h_lo[(size_t)b * H + 256 + t];
    __syncthreads();

    float acc = bh1[j * M + t];
    const float* w = Wh1 + (size_t)j * H * M + t;
#pragma unroll 8
    for (int k = 0; k < H; ++k) acc = fmaf(hs[k], w[(size_t)k * M], acc);

    zs[t] = gelu_exact(acc);
    __syncthreads();

    if (t < HOR) {
        float a = bh2[j * HOR + t];
        const float* w2 = Wh2 + (size_t)j * M * HOR + t;
        for (int m = 0; m < M; ++m) a = fmaf(zs[m], w2[(size_t)m * HOR], a);
        out[(size_t)b * HOR + t] = a;
    }
}

// ---------------------------------------------------------------------------
extern "C" void kernel_launch(void* const* d_in, const int* in_sizes, int n_in,
                              void* d_out, int out_size, void* d_ws, size_t ws_size,
                              hipStream_t stream)
{
    const float* x     = (const float*)d_in[0];
    const int*   joint = (const int*)  d_in[1];
    const float* Wp    = (const float*)d_in[2];
    const float* bp    = (const float*)d_in[3];
    const float* gamma = (const float*)d_in[4];
    const float* beta  = (const float*)d_in[5];
    const float* Wih0  = (const float*)d_in[6];
    const float* Whh0  = (const float*)d_in[7];
    const float* bih0  = (const float*)d_in[8];
    const float* bhh0  = (const float*)d_in[9];
    const float* Wih1  = (const float*)d_in[10];
    const float* Whh1  = (const float*)d_in[11];
    const float* bih1  = (const float*)d_in[12];
    const float* bhh1  = (const float*)d_in[13];
    const float* Wh1   = (const float*)d_in[14];
    const float* bh1   = (const float*)d_in[15];
    const float* Wh2   = (const float*)d_in[16];
    const float* bh2   = (const float*)d_in[17];
    float* out = (float*)d_out;

    char* base = (char*)d_ws;
    size_t off = 0;
    auto take = [&](size_t nbytes) -> void* {
        void* p = base + off;
        off = (off + nbytes + 255) & ~(size_t)255;
        return p;
    };

    bf16* W0hi = (bf16*)take((size_t)G * K0 * 2);
    bf16* W0lo = (bf16*)take((size_t)G * K0 * 2);
    bf16* W1hi = (bf16*)take((size_t)G * K1 * 2);
    bf16* W1lo = (bf16*)take((size_t)G * K1 * 2);
    float* bsum0 = (float*)take(G * 4);
    float* bsum1 = (float*)take(G * 4);

    const size_t states_off = off;
    bf16* h0hi0 = (bf16*)take((size_t)B * H * 2);
    bf16* h0lo0 = (bf16*)take((size_t)B * H * 2);
    bf16* h0hi1 = (bf16*)take((size_t)B * H * 2);
    bf16* h0lo1 = (bf16*)take((size_t)B * H * 2);
    bf16* h1hi0 = (bf16*)take((size_t)B * H * 2);
    bf16* h1lo0 = (bf16*)take((size_t)B * H * 2);
    bf16* h1hi1 = (bf16*)take((size_t)B * H * 2);
    bf16* h1lo1 = (bf16*)take((size_t)B * H * 2);
    float* c0 = (float*)take((size_t)B * H * 4);
    float* c1 = (float*)take((size_t)B * H * 4);
    const size_t states_bytes = off - states_off;

    bf16* ehi = (bf16*)take((size_t)L * B * P * 2);
    bf16* elo = (bf16*)take((size_t)L * B * P * 2);
    int use_elo = (off <= ws_size) ? 1 : 0;
    if (!use_elo) elo = ehi;   // never read/written when use_elo==0

    prep_w0<<<dim3(3, G), 256, 0, stream>>>(Wih0, Whh0, W0hi, W0lo);
    prep_w1<<<dim3(4, G), 256, 0, stream>>>(Wih1, Whh1, W1hi, W1lo);
    prep_bias<<<8, 256, 0, stream>>>(bih0, bhh0, bih1, bhh1, bsum0, bsum1);
    hipMemsetAsync(base + states_off, 0, states_bytes, stream);
    emb_kernel<<<B * L, 256, 0, stream>>>(x, Wp, bp, gamma, beta, ehi, elo, use_elo);

    for (int t = 0; t <= L; ++t) {
        tick_kernel<<<256, 256, 0, stream>>>(
            t, use_elo, ehi, elo, W0hi, W0lo, W1hi, W1lo, bsum0, bsum1,
            h0hi0, h0lo0, h0hi1, h0lo1, h1hi0, h1lo0, h1hi1, h1lo1, c0, c1);
    }

    // final h1 (step 511) was written to buf[(512-1)&1] = buf 1
    head_kernel<<<B, 256, 0, stream>>>(h1hi1, h1lo1, joint, Wh1, bh1, Wh2, bh2, out);
}